// Round 1
// baseline (125.069 us; speedup 1.0000x reference)
//
#include <hip/hip_runtime.h>

typedef _Float16 f16x8 __attribute__((ext_vector_type(8)));
typedef float f32x4 __attribute__((ext_vector_type(4)));

#define MDIM 64000
#define KDIM 512
#define NCOLS 514
#define NPAD 640
#define BM 128
#define BN 128
#define BK 64
#define NT 5  // N tiles

// Build interleaved f16 weight matrix Wb[n][k], n in [0,640):
//   n even -> real_kernel[n/2], n odd -> imag_kernel[n/2], n>=514 -> 0
__global__ void prep_w(const float* __restrict__ rk, const float* __restrict__ ik,
                       _Float16* __restrict__ wb) {
  int n = blockIdx.x;
  int k = threadIdx.x;
  float v = 0.0f;
  if (n < NCOLS) {
    int bin = n >> 1;
    const float* src = (n & 1) ? ik : rk;
    v = src[bin * KDIM + k];
  }
  wb[(size_t)n * KDIM + k] = (_Float16)v;
}

__global__ __launch_bounds__(256, 2)
void dft_gemm(const float* __restrict__ x, const _Float16* __restrict__ wb,
              float* __restrict__ out) {
  __shared__ _Float16 As[BM * BK];
  __shared__ _Float16 Bs[BN * BK];

  const int tid = threadIdx.x;
  const int l   = tid & 63;
  const int wid = tid >> 6;
  const int lr  = l & 15;   // fragment row/col lane index
  const int lg  = l >> 4;   // lane group 0..3
  const int wm  = (wid >> 1) * 64;
  const int wn  = (wid & 1) * 64;

  const int bid = blockIdx.x;
  const int mt  = bid / NT;
  const int nt  = bid - mt * NT;
  const int m0  = mt * BM;
  const int n0  = nt * BN;

  f32x4 acc[4][4] = {};

  const int srow = tid >> 3;  // 0..31
  const int c8   = tid & 7;   // 0..7  (8-element chunk within 64-wide K slab)

  for (int kt = 0; kt < KDIM / BK; ++kt) {
    if (kt) __syncthreads();

    // ---- stage A: x fp32 -> f16 LDS, XOR-swizzled ----
#pragma unroll
    for (int s = 0; s < 4; ++s) {
      int row = s * 32 + srow;  // 0..127
      const float4* p = reinterpret_cast<const float4*>(
          x + (size_t)(m0 + row) * KDIM + kt * BK + c8 * 8);
      float4 v0 = p[0];
      float4 v1 = p[1];
      f16x8 h;
      h[0] = (_Float16)v0.x; h[1] = (_Float16)v0.y;
      h[2] = (_Float16)v0.z; h[3] = (_Float16)v0.w;
      h[4] = (_Float16)v1.x; h[5] = (_Float16)v1.y;
      h[6] = (_Float16)v1.z; h[7] = (_Float16)v1.w;
      int e = row * BK + ((c8 ^ (row & 7)) << 3);
      *reinterpret_cast<f16x8*>(&As[e]) = h;
    }
    // ---- stage B: Wb f16 -> LDS, XOR-swizzled ----
#pragma unroll
    for (int s = 0; s < 4; ++s) {
      int row = s * 32 + srow;  // n_local 0..127
      f16x8 b = *reinterpret_cast<const f16x8*>(
          wb + (size_t)(n0 + row) * KDIM + kt * BK + c8 * 8);
      int e = row * BK + ((c8 ^ (row & 7)) << 3);
      *reinterpret_cast<f16x8*>(&Bs[e]) = b;
    }
    __syncthreads();

    // ---- MFMA: 2 k-subtiles of 32, 4x4 fragments of 16x16 per wave ----
#pragma unroll
    for (int ks = 0; ks < 2; ++ks) {
      f16x8 av[4], bv[4];
#pragma unroll
      for (int fm = 0; fm < 4; ++fm) {
        int m = wm + fm * 16 + lr;
        int e = (m * BK + ks * 32 + lg * 8) ^ ((m & 7) << 3);
        av[fm] = *reinterpret_cast<const f16x8*>(&As[e]);
      }
#pragma unroll
      for (int fn = 0; fn < 4; ++fn) {
        int n = wn + fn * 16 + lr;
        int e = (n * BK + ks * 32 + lg * 8) ^ ((n & 7) << 3);
        bv[fn] = *reinterpret_cast<const f16x8*>(&Bs[e]);
      }
#pragma unroll
      for (int fm = 0; fm < 4; ++fm)
#pragma unroll
        for (int fn = 0; fn < 4; ++fn)
          acc[fm][fn] = __builtin_amdgcn_mfma_f32_16x16x32_f16(
              av[fm], bv[fn], acc[fm][fn], 0, 0, 0);
    }
  }

  // ---- epilogue: C/D layout col=lane&15, row=(lane>>4)*4+reg ----
#pragma unroll
  for (int fm = 0; fm < 4; ++fm) {
#pragma unroll
    for (int r = 0; r < 4; ++r) {
      int row = m0 + wm + fm * 16 + lg * 4 + r;
      size_t base = (size_t)row * NCOLS;
#pragma unroll
      for (int fn = 0; fn < 4; ++fn) {
        int col = n0 + wn + fn * 16 + lr;
        if (col < NCOLS) out[base + col] = acc[fm][fn][r];
      }
    }
  }
}

extern "C" void kernel_launch(void* const* d_in, const int* in_sizes, int n_in,
                              void* d_out, int out_size, void* d_ws, size_t ws_size,
                              hipStream_t stream) {
  const float* x  = (const float*)d_in[0];
  const float* rk = (const float*)d_in[1];
  const float* ik = (const float*)d_in[2];
  float* out = (float*)d_out;
  _Float16* wb = (_Float16*)d_ws;  // 640*512*2 B = 655 KB scratch

  prep_w<<<dim3(NPAD), dim3(KDIM), 0, stream>>>(rk, ik, wb);

  dim3 grid((MDIM / BM) * NT);  // 500 M-tiles x 5 N-tiles, M-major
  dft_gemm<<<grid, dim3(256), 0, stream>>>(x, wb, out);
}

// Round 2
// 81.900 us; speedup vs baseline: 1.5271x; 1.5271x over previous
//
#include <hip/hip_runtime.h>

typedef _Float16 f16x8 __attribute__((ext_vector_type(8)));
typedef float f32x4 __attribute__((ext_vector_type(4)));

#define MDIM 64000
#define KDIM 512
#define NCOLS 514
#define NPAD 640
#define BM 128
#define BN 128
#define BK 64
#define NT 5  // N tiles
#define NWG 2500

// global -> LDS direct DMA, 16B per lane, LDS dest = wave-uniform base + lane*16
#define GLOAD_LDS16(g, l)                                        \
  __builtin_amdgcn_global_load_lds(                              \
      (const __attribute__((address_space(1))) void*)(g),        \
      (__attribute__((address_space(3))) void*)(l), 16, 0, 0)

// Build interleaved f16 weight matrix Wb[n][k], n in [0,640):
//   n even -> real_kernel[n/2], n odd -> imag_kernel[n/2], n>=514 -> 0
__global__ void prep_w(const float* __restrict__ rk, const float* __restrict__ ik,
                       _Float16* __restrict__ wb) {
  int n = blockIdx.x;
  int k = threadIdx.x;
  float v = 0.0f;
  if (n < NCOLS) {
    int bin = n >> 1;
    const float* src = (n & 1) ? ik : rk;
    v = src[bin * KDIM + k];
  }
  wb[(size_t)n * KDIM + k] = (_Float16)v;
}

__global__ __launch_bounds__(256, 3)
void dft_gemm(const float* __restrict__ x, const _Float16* __restrict__ wb,
              float* __restrict__ out) {
  // A tile kept in f32 (32 KB), converted to f16 on fragment read.
  // Content is chunk-swizzled: phys 16B-chunk c holds logical chunk c^(row&7),
  // achieved by inverse-swizzling the GLOBAL source address (LDS dest linear).
  __shared__ float As[BM * BK];      // 32 KB
  __shared__ _Float16 Bs[BN * BK];   // 16 KB

  const int tid = threadIdx.x;
  const int l   = tid & 63;
  const int w   = tid >> 6;
  const int lr  = l & 15;   // fragment row/col lane index
  const int lg  = l >> 4;   // lane k-group 0..3
  const int wm  = (w >> 1) * 64;
  const int wn  = (w & 1) * 64;

  // T1: bijective chunked XCD swizzle (m204). Consecutive wgid -> same XCD,
  // so the 5 N-tile blocks of one M-tile share the x slab in one L2.
  const int xcd = blockIdx.x & 7;
  const int lid = blockIdx.x >> 3;
  const int q   = NWG >> 3;          // 312
  const int r   = NWG & 7;           // 4
  const int wgid = (xcd < r) ? xcd * (q + 1) + lid
                             : r * (q + 1) + (xcd - r) * q + lid;
  const int mt = wgid / NT;
  const int nt = wgid - mt * NT;
  const int m0 = mt * BM;
  const int n0 = nt * BN;

  f32x4 acc[4][4] = {};

  // staging lane decomposition
  const int arl = l >> 4;  // A: row-within-issue 0..3
  const int acp = l & 15;  // A: phys 16B chunk 0..15 (4 floats)
  const int brl = l >> 3;  // B: row-within-issue 0..7
  const int bcp = l & 7;   // B: phys 16B chunk 0..7 (8 f16)

  for (int kt = 0; kt < KDIM / BK; ++kt) {
    if (kt) __syncthreads();

    // ---- stage A: x f32 -> LDS via global_load_lds, source pre-swizzled ----
#pragma unroll
    for (int s = 0; s < 8; ++s) {
      int r0  = w * 32 + s * 4;            // wave-uniform
      int row = r0 + arl;
      int cl  = acp ^ (row & 7);           // logical chunk to fetch
      const float* g = x + (size_t)(m0 + row) * KDIM + kt * BK + cl * 4;
      GLOAD_LDS16(g, &As[r0 * BK]);
    }
    // ---- stage B: wb f16 -> LDS via global_load_lds, source pre-swizzled ----
#pragma unroll
    for (int s = 0; s < 4; ++s) {
      int r0  = w * 32 + s * 8;            // wave-uniform
      int row = r0 + brl;
      int cl  = bcp ^ (row & 7);
      const _Float16* g = wb + (size_t)(n0 + row) * KDIM + kt * BK + cl * 8;
      GLOAD_LDS16(g, &Bs[r0 * BK]);
    }
    __syncthreads();  // compiler drains vmcnt(0) before s_barrier

    // ---- MFMA: 2 k-subtiles of 32, 4x4 fragments of 16x16 per wave ----
#pragma unroll
    for (int ks = 0; ks < 2; ++ks) {
      f16x8 av[4], bv[4];
#pragma unroll
      for (int fm = 0; fm < 4; ++fm) {
        int row = wm + fm * 16 + lr;
        int c0  = ks * 8 + lg * 2;         // logical 16B chunk (4 f32)
        int sw  = row & 7;
        f32x4 lo = *reinterpret_cast<const f32x4*>(&As[row * BK + ((c0 ^ sw) << 2)]);
        f32x4 hi = *reinterpret_cast<const f32x4*>(&As[row * BK + (((c0 + 1) ^ sw) << 2)]);
        f16x8 h;
        h[0] = (_Float16)lo[0]; h[1] = (_Float16)lo[1];
        h[2] = (_Float16)lo[2]; h[3] = (_Float16)lo[3];
        h[4] = (_Float16)hi[0]; h[5] = (_Float16)hi[1];
        h[6] = (_Float16)hi[2]; h[7] = (_Float16)hi[3];
        av[fm] = h;
      }
#pragma unroll
      for (int fn = 0; fn < 4; ++fn) {
        int row = wn + fn * 16 + lr;
        int c   = (ks * 4 + lg) ^ (row & 7);  // 16B chunk (8 f16)
        bv[fn] = *reinterpret_cast<const f16x8*>(&Bs[row * BK + (c << 3)]);
      }
#pragma unroll
      for (int fm = 0; fm < 4; ++fm)
#pragma unroll
        for (int fn = 0; fn < 4; ++fn)
          acc[fm][fn] = __builtin_amdgcn_mfma_f32_16x16x32_f16(
              av[fm], bv[fn], acc[fm][fn], 0, 0, 0);
    }
  }

  // ---- epilogue: C/D layout col=lane&15, row=(lane>>4)*4+reg ----
#pragma unroll
  for (int fm = 0; fm < 4; ++fm) {
#pragma unroll
    for (int rr = 0; rr < 4; ++rr) {
      int row = m0 + wm + fm * 16 + lg * 4 + rr;
      size_t base = (size_t)row * NCOLS;
#pragma unroll
      for (int fn = 0; fn < 4; ++fn) {
        int col = n0 + wn + fn * 16 + lr;
        if (col < NCOLS) out[base + col] = acc[fm][fn][rr];
      }
    }
  }
}

extern "C" void kernel_launch(void* const* d_in, const int* in_sizes, int n_in,
                              void* d_out, int out_size, void* d_ws, size_t ws_size,
                              hipStream_t stream) {
  const float* x  = (const float*)d_in[0];
  const float* rk = (const float*)d_in[1];
  const float* ik = (const float*)d_in[2];
  float* out = (float*)d_out;
  _Float16* wb = (_Float16*)d_ws;  // 640*512*2 B = 655 KB scratch

  prep_w<<<dim3(NPAD), dim3(KDIM), 0, stream>>>(rk, ik, wb);

  dim3 grid(NWG);  // 500 M-tiles x 5 N-tiles, M-major via chunked XCD swizzle
  dft_gemm<<<grid, dim3(256), 0, stream>>>(x, wb, out);
}